// Round 4
// baseline (47.835 us; speedup 1.0000x reference)
//
#include <hip/hip_runtime.h>

#define KW   7
#define CIN  64
#define COUT 64
#define HH   64
#define WW   64
#define BB   4
#define HW   (HH * WW)

#define RS   8            // output rows per block
#define GC   4            // channels per block
#define SR   (RS + 6)     // 14 staged k/v rows (3 halo each side)
#define SC   74           // 72 used cols padded to 74 (bank stagger for the
                          //   4-row lane32-63 offset: 4*74 mod 32 = 8)
#define QC   66           // q tile: 64 cols padded to 66

// ---------------------------------------------------------------------------
// Fully fused: 1x1-conv q/k/v projection into LDS + 7x7 local attention.
// No global q/k/v round-trip, no second dispatch, no inter-kernel L2 flush.
// Phase 1: each thread projects ~4 staged pixels (k,v over 14x64 interior,
//          zeros on halo; q folded into the same x-load loop for the 8
//          interior rows). Padded positions of k_full/v_full are exactly 0
//          (1x1 conv of zero padding, no bias) -> synthesized zeros.
// Phase 2: thread = 4 rows x 2 cols x 1 channel; streams 10 shared rows via
//          aligned float2 ds_reads; softmax without max-subtraction
//          (|logit| < ~25 -> exp2 arg safe in f32); rel row/col select
//          hoisted via template (use_h is block-uniform).
// ---------------------------------------------------------------------------

template <bool USE_H>
__device__ __forceinline__ void attn_phase(
    const float (*ktp)[SC], const float (*vtp)[SC],
    const float q2[4][2], const float rel[KW],
    int tx, int r4, float s[4][2], float acc[4][2])
{
    #pragma unroll
    for (int rr = 0; rr < 10; ++rr) {
        const int srow = r4 * 4 + rr;
        float kx[10], vx[10];
        #pragma unroll
        for (int s5 = 0; s5 < 5; ++s5) {
            *(float2*)&kx[2 * s5] = *(const float2*)&ktp[srow][2 * tx + 2 * s5];
            *(float2*)&vx[2 * s5] = *(const float2*)&vtp[srow][2 * tx + 2 * s5];
        }
        #pragma unroll
        for (int r = 0; r < 4; ++r) {
            const int i = rr - r;                  // window row index
            if (i < 0 || i > 6) continue;          // compile-time pruned
            #pragma unroll
            for (int c = 0; c < 2; ++c) {
                #pragma unroll
                for (int j = 0; j < KW; ++j) {
                    const float relv = USE_H ? rel[i] : rel[j];
                    const float e = __builtin_amdgcn_exp2f(
                        q2[r][c] * (kx[c + 1 + j] + relv));
                    s[r][c] += e;
                    acc[r][c] = fmaf(e, vx[c + 1 + j], acc[r][c]);
                }
            }
        }
    }
}

__global__ __launch_bounds__(256) void fused_attnconv_kernel(
    const float* __restrict__ x,  const float* __restrict__ wq,
    const float* __restrict__ wk, const float* __restrict__ wv,
    const float* __restrict__ rel_h, const float* __restrict__ rel_w,
    float* __restrict__ out)
{
    __shared__ float kt[GC][SR][SC];
    __shared__ float vt[GC][SR][SC];
    __shared__ float qt[GC][RS][QC];

    const int tid = threadIdx.x;
    const int h0  = blockIdx.x * RS;
    const int og  = blockIdx.y * GC;
    const int b   = blockIdx.z;

    // ---------------- Phase 1: projection into LDS ----------------
    const float* xb  = x  + (size_t)b * CIN * HW;
    const float* wqr = wq + og * CIN;
    const float* wkr = wk + og * CIN;
    const float* wvr = wv + og * CIN;

    #pragma unroll
    for (int it = 0; it < 4; ++it) {
        const int slot = tid + it * 256;           // covers 14*72 = 1008 slots
        if (slot < SR * 72) {
            const int pr = slot / 72;              // staged row 0..13
            const int pc = slot - pr * 72;         // staged col 0..71
            const int gr = h0 - 3 + pr;            // global row
            const int gc = pc - 4;                 // global col
            float ak[GC] = {0.f, 0.f, 0.f, 0.f};
            float av[GC] = {0.f, 0.f, 0.f, 0.f};
            float aq[GC] = {0.f, 0.f, 0.f, 0.f};
            const bool interior = ((unsigned)gr < HH) & ((unsigned)gc < WW);
            const bool qrow     = (pr >= 3) & (pr < 3 + RS);
            if (interior) {
                const float* xp = xb + (size_t)gr * WW + gc;
                if (qrow) {
                    #pragma unroll
                    for (int c = 0; c < CIN; ++c) {
                        const float xv = xp[(size_t)c * HW];
                        #pragma unroll
                        for (int n = 0; n < GC; ++n) {
                            ak[n] = fmaf(xv, wkr[n * CIN + c], ak[n]);
                            av[n] = fmaf(xv, wvr[n * CIN + c], av[n]);
                            aq[n] = fmaf(xv, wqr[n * CIN + c], aq[n]);
                        }
                    }
                } else {
                    #pragma unroll
                    for (int c = 0; c < CIN; ++c) {
                        const float xv = xp[(size_t)c * HW];
                        #pragma unroll
                        for (int n = 0; n < GC; ++n) {
                            ak[n] = fmaf(xv, wkr[n * CIN + c], ak[n]);
                            av[n] = fmaf(xv, wvr[n * CIN + c], av[n]);
                        }
                    }
                }
            }
            #pragma unroll
            for (int n = 0; n < GC; ++n) {
                kt[n][pr][pc] = ak[n];
                vt[n][pr][pc] = av[n];
            }
            if (qrow & ((unsigned)gc < WW) & ((unsigned)gr < HH)) {
                #pragma unroll
                for (int n = 0; n < GC; ++n) qt[n][pr - 3][gc] = aq[n];
            }
        }
    }
    __syncthreads();

    // ---------------- Phase 2: local attention ----------------
    const int ch = tid >> 6;          // 0..3
    const int r4 = (tid >> 5) & 1;    // rows r4*4 .. r4*4+3 of the strip
    const int tx = tid & 31;          // column pair
    const int o  = og + ch;
    const bool use_h = (o < COUT / 2);             // block-uniform

    float rel[KW];
    const float* rp = use_h ? (rel_h + o * KW) : (rel_w + (o - COUT / 2) * KW);
    #pragma unroll
    for (int t = 0; t < KW; ++t) rel[t] = rp[t];

    float q2[4][2];
    #pragma unroll
    for (int r = 0; r < 4; ++r) {
        const float2 qv = *(const float2*)&qt[ch][r4 * 4 + r][2 * tx];
        q2[r][0] = qv.x * 1.44269504088896f;       // fold log2(e)
        q2[r][1] = qv.y * 1.44269504088896f;
    }

    float s[4][2]   = {{0.f, 0.f}, {0.f, 0.f}, {0.f, 0.f}, {0.f, 0.f}};
    float acc[4][2] = {{0.f, 0.f}, {0.f, 0.f}, {0.f, 0.f}, {0.f, 0.f}};

    if (use_h) attn_phase<true >(kt[ch], vt[ch], q2, rel, tx, r4, s, acc);
    else       attn_phase<false>(kt[ch], vt[ch], q2, rel, tx, r4, s, acc);

    const size_t plane = ((size_t)b * COUT + o) * HW;
    #pragma unroll
    for (int r = 0; r < 4; ++r) {
        float2 ov;
        ov.x = acc[r][0] * __builtin_amdgcn_rcpf(s[r][0]);
        ov.y = acc[r][1] * __builtin_amdgcn_rcpf(s[r][1]);
        *(float2*)&out[plane + (size_t)(h0 + r4 * 4 + r) * WW + 2 * tx] = ov;
    }
}

extern "C" void kernel_launch(void* const* d_in, const int* in_sizes, int n_in,
                              void* d_out, int out_size, void* d_ws, size_t ws_size,
                              hipStream_t stream) {
    const float* x     = (const float*)d_in[0];
    const float* wq    = (const float*)d_in[1];
    const float* wk    = (const float*)d_in[2];
    const float* wv    = (const float*)d_in[3];
    const float* rel_h = (const float*)d_in[4];
    const float* rel_w = (const float*)d_in[5];
    float* out = (float*)d_out;

    dim3 grid(HH / RS, COUT / GC, BB);   // (8, 16, 4) = 512 blocks
    fused_attnconv_kernel<<<grid, 256, 0, stream>>>(
        x, wq, wk, wv, rel_h, rel_w, out);
}

// Round 5
// 32.607 us; speedup vs baseline: 1.4670x; 1.4670x over previous
//
#include <hip/hip_runtime.h>

#define KW   7
#define CIN  64
#define COUT 64
#define HH   64
#define WW   64
#define BB   4
#define HW   (HH * WW)

typedef __attribute__((ext_vector_type(8))) short short8v;  // 8 bf16 (4 VGPRs)
typedef __attribute__((ext_vector_type(4))) float f32x4;

__device__ __forceinline__ unsigned pack_bf16(float lo, float hi) {
    unsigned a = __builtin_bit_cast(unsigned, lo);
    unsigned b = __builtin_bit_cast(unsigned, hi);
    a = (a + 0x7fffu + ((a >> 16) & 1u)) >> 16;   // RNE f32->bf16
    b = (b + 0x7fffu + ((b >> 16) & 1u)) >> 16;
    return a | (b << 16);
}

// ---------------------------------------------------------------------------
// Kernel 1: q/k/v 1x1-conv projection as ONE bf16 MFMA GEMM.
//   D[192 x 64px] = Wstk[192 x 64] @ x[b][64 x 64px]   per (block, batch)
// Wstk = rows 0-63 wq, 64-127 wk, 128-191 wv (bf16, staged once in LDS).
// A/B fragments use the SAME lane->k mapping (k = (lane>>4)*8 + i), so any
// error in the guessed k-permutation cancels in the dot product; the C/D
// mapping (col = lane&15, row = (lane>>4)*4 + reg) is the HW-verified one.
// Padded k/v positions are exactly 0 (1x1 conv of zero pad) -> K2 zeros.
// ---------------------------------------------------------------------------
#define LWROW 36   // dwords per LDS row (32 bf16-pairs, padded to %4==0)

__global__ __launch_bounds__(256) void proj_mfma_kernel(
    const float* __restrict__ x,  const float* __restrict__ wq,
    const float* __restrict__ wk, const float* __restrict__ wv,
    float* __restrict__ qb, float* __restrict__ kb, float* __restrict__ vb)
{
    __shared__ unsigned lw[192 * LWROW];   // W as bf16 pairs
    __shared__ unsigned xt[64 * LWROW];    // x tile as bf16 pairs, pixel-major

    const int tid = threadIdx.x;
    const int p0  = blockIdx.x * 64;       // pixel tile
    const int b   = blockIdx.y;

    // Stage stacked W (192 x 64 f32 -> bf16 pairs).
    const float* wsel[3] = {wq, wk, wv};
    for (int idx = tid; idx < 192 * 32; idx += 256) {
        const int r  = idx >> 5;
        const int dw = idx & 31;
        const float* wr = wsel[r >> 6] + (r & 63) * CIN + dw * 2;
        lw[r * LWROW + dw] = pack_bf16(wr[0], wr[1]);
    }
    // Stage x tile (64 pixels x 64 ch), transposed to pixel-major rows.
    {
        const int p = tid & 63, grp = tid >> 6;
        const float* xb = x + (size_t)b * CIN * HW + p0 + p;
        #pragma unroll
        for (int d = 0; d < 8; ++d) {
            const int dw = grp * 8 + d;
            const float f0 = xb[(size_t)(2 * dw)     * HW];
            const float f1 = xb[(size_t)(2 * dw + 1) * HW];
            xt[p * LWROW + dw] = pack_bf16(f0, f1);
        }
    }
    __syncthreads();

    const int lane = tid & 63;
    const int wid  = tid >> 6;             // wave = 16-pixel n-tile
    const int col  = lane & 15;
    const int lg   = lane >> 4;
    const int n0   = wid * 16;

    short8v bfrag[2];
    #pragma unroll
    for (int kc = 0; kc < 2; ++kc)
        bfrag[kc] = *(const short8v*)&xt[(n0 + col) * LWROW + kc * 16 + lg * 4];

    float* osel[3] = {qb, kb, vb};
    #pragma unroll
    for (int mt = 0; mt < 12; ++mt) {
        f32x4 acc = {0.f, 0.f, 0.f, 0.f};
        #pragma unroll
        for (int kc = 0; kc < 2; ++kc) {
            const short8v afrag =
                *(const short8v*)&lw[(mt * 16 + col) * LWROW + kc * 16 + lg * 4];
            acc = __builtin_amdgcn_mfma_f32_16x16x32_bf16(afrag, bfrag[kc], acc, 0, 0, 0);
        }
        const int mat = mt >> 2;                       // 0=q, 1=k, 2=v
        const int chb = (mt & 3) * 16 + lg * 4;        // channel of acc[0]
        float* dst = osel[mat] + ((size_t)b * COUT + chb) * HW + p0 + n0 + col;
        #pragma unroll
        for (int r = 0; r < 4; ++r) dst[(size_t)r * HW] = acc[r];
    }
}

// ---------------------------------------------------------------------------
// Kernel 2: per-channel 7x7 local attention (R2's measured-best version).
// Block (64,4) = 4 output rows of one (b,o) plane; k/v halo rows staged in
// LDS with zero borders; softmax without max-subtraction (safe in f32).
// ---------------------------------------------------------------------------
__global__ __launch_bounds__(256) void attn_kernel(
    const float* __restrict__ qb, const float* __restrict__ kb,
    const float* __restrict__ vb, const float* __restrict__ rel_h,
    const float* __restrict__ rel_w, float* __restrict__ out)
{
    __shared__ float kt[10][72];
    __shared__ float vt[10][72];

    const int tx = threadIdx.x;               // w: 0..63 (lane)
    const int ty = threadIdx.y;               // row within tile: 0..3
    const int h0 = blockIdx.x * 4;
    const int o  = blockIdx.y;
    const int b  = blockIdx.z;
    const size_t plane = ((size_t)b * COUT + o) * HW;

    for (int rr = ty; rr < 10; rr += 4) {
        const int gr = h0 - 3 + rr;
        float kk = 0.f, vv = 0.f;
        if (gr >= 0 && gr < HH) {
            kk = kb[plane + (size_t)gr * WW + tx];
            vv = vb[plane + (size_t)gr * WW + tx];
        }
        kt[rr][tx + 3] = kk;
        vt[rr][tx + 3] = vv;
        if (tx < 3) {
            kt[rr][tx] = 0.f;      vt[rr][tx] = 0.f;
            kt[rr][tx + 67] = 0.f; vt[rr][tx + 67] = 0.f;
        }
    }
    __syncthreads();

    const float q  = qb[plane + (size_t)(h0 + ty) * WW + tx];
    const float q2 = q * 1.44269504088896f;   // fold log2(e)

    const bool use_h = (o < COUT / 2);        // block-uniform
    const float* rp = use_h ? (rel_h + o * KW) : (rel_w + (o - COUT / 2) * KW);
    float qadd[KW];
    #pragma unroll
    for (int t = 0; t < KW; ++t) qadd[t] = q2 * rp[t];

    float s = 0.f, acc = 0.f;
    if (use_h) {
        #pragma unroll
        for (int i = 0; i < KW; ++i) {
            #pragma unroll
            for (int j = 0; j < KW; ++j) {
                const float e = __builtin_amdgcn_exp2f(
                    fmaf(q2, kt[ty + i][tx + j], qadd[i]));
                s += e;
                acc = fmaf(e, vt[ty + i][tx + j], acc);
            }
        }
    } else {
        #pragma unroll
        for (int i = 0; i < KW; ++i) {
            #pragma unroll
            for (int j = 0; j < KW; ++j) {
                const float e = __builtin_amdgcn_exp2f(
                    fmaf(q2, kt[ty + i][tx + j], qadd[j]));
                s += e;
                acc = fmaf(e, vt[ty + i][tx + j], acc);
            }
        }
    }

    out[plane + (size_t)(h0 + ty) * WW + tx] = acc / s;
}

extern "C" void kernel_launch(void* const* d_in, const int* in_sizes, int n_in,
                              void* d_out, int out_size, void* d_ws, size_t ws_size,
                              hipStream_t stream) {
    const float* x     = (const float*)d_in[0];
    const float* wq    = (const float*)d_in[1];
    const float* wk    = (const float*)d_in[2];
    const float* wv    = (const float*)d_in[3];
    const float* rel_h = (const float*)d_in[4];
    const float* rel_w = (const float*)d_in[5];
    float* out = (float*)d_out;

    float* qb = (float*)d_ws;                 // 3 x BB*COUT*HW floats = 12 MB
    float* kb = qb + (size_t)BB * COUT * HW;
    float* vb = kb + (size_t)BB * COUT * HW;

    dim3 g1(HW / 64, BB);                     // (64, 4) blocks, 256 thr
    proj_mfma_kernel<<<g1, 256, 0, stream>>>(x, wq, wk, wv, qb, kb, vb);

    dim3 g2(HH / 4, COUT, BB);                // (16, 64, 4)
    dim3 b2(64, 4);
    attn_kernel<<<g2, b2, 0, stream>>>(qb, kb, vb, rel_h, rel_w, out);
}